// Round 10
// baseline (240.505 us; speedup 1.0000x reference)
//
#include <hip/hip_runtime.h>
#include <hip/hip_bf16.h>

#define T_DIM 4096
#define B_DIM 32
#define I_DIM 512
#define O_DIM 512
#define M_DIM (T_DIM * B_DIM)   // 131072
#define PARAM 0.1f
#define ISCALE 1.1111112f       // 1/(1-p)

#define STRIP 32
#define TAPS 8                  // p^8 = 1e-8 << bf16 eps

#define BM 256
#define BN 256
#define BK 64
#define NK (I_DIM / BK)         // 8

typedef __attribute__((ext_vector_type(8))) short bf16x8;
typedef __attribute__((ext_vector_type(4))) float f32x4;

__device__ __forceinline__ unsigned short f2bf(float f) {
    union { __hip_bfloat16 b; unsigned short u; } cv;
    cv.b = __float2bfloat16(f);
    return cv.u;
}

// --- W fp32 -> bf16 (0.5 MB, ws offset 0) ---
__global__ __launch_bounds__(256) void wcvt_kernel(const float* __restrict__ W,
                                                   unsigned short* __restrict__ Wb) {
    const int i = (blockIdx.x * 256 + threadIdx.x) * 4;
    f32x4 v = *(const f32x4*)(W + i);
    ushort4 o;
    o.x = f2bf(v[0]); o.y = f2bf(v[1]); o.z = f2bf(v[2]); o.w = f2bf(v[3]);
    *(ushort4*)(Wb + i) = o;
}

// --- EMA over raw X (linearity: EMA(XW+b) = EMA(X)W + s[t]*b). Strip-parallel,
// TAPS warm-up reads raw X; bf16 output compacted into d_ws. ---
__global__ __launch_bounds__(256) void xema_kernel(const float* __restrict__ X,
                                                   unsigned short* __restrict__ Xv) {
    const int s   = blockIdx.x >> 4;                 // strip 0..127
    const int blk = blockIdx.x & 15;
    const int col = (blk * 256 + threadIdx.x) * 4;
    const int t0  = s * STRIP;
    const int b   = col >> 9;
    const int o   = col & 511;

    const float* xin = X + (size_t)t0 * 16384 + col;
    unsigned short* xout = Xv + (size_t)(t0 * 32 + b) * 512 + o;

    f32x4 v = {0.f, 0.f, 0.f, 0.f};
    if (s > 0) {
        const float* w = xin - (size_t)TAPS * 16384;
        #pragma unroll
        for (int j = 0; j < TAPS; ++j)
            v = PARAM * v + *(const f32x4*)(w + (size_t)j * 16384);
    }

    f32x4 bufA[4], bufB[4];
    #pragma unroll
    for (int j = 0; j < 4; ++j) bufA[j] = *(const f32x4*)(xin + (size_t)j * 16384);

    #pragma unroll
    for (int i = 0; i < STRIP; i += 8) {
        #pragma unroll
        for (int j = 0; j < 4; ++j)
            bufB[j] = *(const f32x4*)(xin + (size_t)(i + 4 + j) * 16384);
        #pragma unroll
        for (int j = 0; j < 4; ++j) {
            v = PARAM * v + bufA[j];
            ushort4 pk; pk.x = f2bf(v[0]); pk.y = f2bf(v[1]); pk.z = f2bf(v[2]); pk.w = f2bf(v[3]);
            *(ushort4*)(xout + (size_t)(i + j) * 16384) = pk;
        }
        if (i + 8 < STRIP) {
            #pragma unroll
            for (int j = 0; j < 4; ++j)
                bufA[j] = *(const f32x4*)(xin + (size_t)(i + 8 + j) * 16384);
        }
        #pragma unroll
        for (int j = 0; j < 4; ++j) {
            v = PARAM * v + bufB[j];
            ushort4 pk; pk.x = f2bf(v[0]); pk.y = f2bf(v[1]); pk.z = f2bf(v[2]); pk.w = f2bf(v[3]);
            *(ushort4*)(xout + (size_t)(i + 4 + j) * 16384) = pk;
        }
    }
}

// --- GEMM: m201-style 256x256 8-phase pipeline, BK=64, 512 thr (2Mx4N waves,
// wave-tile 128x64, acc 8x4). LDS 128KB = 2dbuf x (A 32KB + B 32KB), 1 blk/CU.
// Per K-tile: 4 C-quadrant phases {ds_reads||stage -> s_barrier -> lgkmcnt(0)
// -> setprio MFMA x16 -> s_barrier}; full next-tile prefetch at q0; vmcnt(0)
// only at q3 (loads flew 3 phases). Involution swizzle c^(r&7) both sides. ---
__global__ __launch_bounds__(512, 2) void gemm_kernel(const unsigned short* __restrict__ Xv,
                                                      const unsigned short* __restrict__ Wb,
                                                      const float* __restrict__ bias,
                                                      float* __restrict__ Y) {
    __shared__ __align__(16) short As[2][BM * BK];   // 32 KB x2
    __shared__ __align__(16) short Bs[2][BN * BK];   // 32 KB x2

    const int tid  = threadIdx.x;
    const int lane = tid & 63;
    const int wave = tid >> 6;        // 0..7
    const int wm   = wave >> 2;       // 0..1 (128-row half)
    const int wn   = wave & 3;        // 0..3 (64-col quarter)

    // 1024 blocks, nwg%8==0: xcd = bid&7, bn-pair of one mt adjacent per XCD.
    const int bid  = blockIdx.x;
    const int swz  = (bid & 7) * 128 + (bid >> 3);
    const int bn   = swz & 1;
    const int mt   = swz >> 1;                    // 0..511
    const int row0 = mt * BM;
    const int col0 = bn * BN;

    // Staging: 16B chunks, 8 per 128B k-window; r&7 = (tid>>3)&7 for every set
    // -> swizzled source chunk cs is per-thread constant.
    const int cs = (tid & 7) ^ ((tid >> 3) & 7);
    const unsigned short* aSrc = Xv + (size_t)(row0 + (tid >> 3)) * 512 + cs * 8;
    const unsigned short* bSrc = Wb + (size_t)(col0 + (tid >> 3)) * 512 + cs * 8;

    // Full K-tile stage: A 32KB (4 loads/thr) + B 32KB (4 loads/thr).
    #define STAGE_TILE(d, kt)                                                         \
        do {                                                                          \
            _Pragma("unroll")                                                         \
            for (int s_ = 0; s_ < 4; ++s_)                                            \
                __builtin_amdgcn_global_load_lds(                                     \
                    (const __attribute__((address_space(1))) unsigned int*)(aSrc + (size_t)s_ * 64 * 512 + (kt) * 64), \
                    (__attribute__((address_space(3))) unsigned int*)(&As[d][0] + (s_ * 512 + tid) * 8),              \
                    16, 0, 0);                                                        \
            _Pragma("unroll")                                                         \
            for (int s_ = 0; s_ < 4; ++s_)                                            \
                __builtin_amdgcn_global_load_lds(                                     \
                    (const __attribute__((address_space(1))) unsigned int*)(bSrc + (size_t)s_ * 64 * 512 + (kt) * 64), \
                    (__attribute__((address_space(3))) unsigned int*)(&Bs[d][0] + (s_ * 512 + tid) * 8),              \
                    16, 0, 0);                                                        \
        } while (0)

    f32x4 acc[8][4] = {};
    bf16x8 af[4][2];     // current row-group A frags (reused across 2 phases)
    bf16x8 bf2[2][2];    // current col-group B frags

    #define READ_A(d, rg)                                                             \
        do {                                                                          \
            _Pragma("unroll")                                                         \
            for (int m_ = 0; m_ < 4; ++m_)                                            \
                _Pragma("unroll")                                                     \
                for (int kk_ = 0; kk_ < 2; ++kk_) {                                   \
                    const int r_  = wm * 128 + (rg) * 64 + m_ * 16 + (lane & 15);     \
                    const int cc_ = kk_ * 4 + (lane >> 4);                            \
                    af[m_][kk_] = *(const bf16x8*)((const char*)&As[d][0] + r_ * 128 + ((cc_ ^ (r_ & 7)) << 4)); \
                }                                                                     \
        } while (0)

    #define READ_B(d, cg)                                                             \
        do {                                                                          \
            _Pragma("unroll")                                                         \
            for (int n_ = 0; n_ < 2; ++n_)                                            \
                _Pragma("unroll")                                                     \
                for (int kk_ = 0; kk_ < 2; ++kk_) {                                   \
                    const int r_  = wn * 64 + (cg) * 32 + n_ * 16 + (lane & 15);      \
                    const int cc_ = kk_ * 4 + (lane >> 4);                            \
                    bf2[n_][kk_] = *(const bf16x8*)((const char*)&Bs[d][0] + r_ * 128 + ((cc_ ^ (r_ & 7)) << 4)); \
                }                                                                     \
        } while (0)

    #define MFMA_Q(rg, cg)                                                            \
        do {                                                                          \
            __builtin_amdgcn_s_setprio(1);                                            \
            _Pragma("unroll")                                                         \
            for (int kk_ = 0; kk_ < 2; ++kk_)                                         \
                _Pragma("unroll")                                                     \
                for (int m_ = 0; m_ < 4; ++m_)                                        \
                    _Pragma("unroll")                                                 \
                    for (int n_ = 0; n_ < 2; ++n_)                                    \
                        acc[(rg) * 4 + m_][(cg) * 2 + n_] =                           \
                            __builtin_amdgcn_mfma_f32_16x16x32_bf16(                  \
                                af[m_][kk_], bf2[n_][kk_],                            \
                                acc[(rg) * 4 + m_][(cg) * 2 + n_], 0, 0, 0);          \
            __builtin_amdgcn_s_setprio(0);                                            \
        } while (0)

    #define PHASE_SYNC()                                                              \
        do {                                                                          \
            __builtin_amdgcn_s_barrier();                                             \
            asm volatile("s_waitcnt lgkmcnt(0)" ::: "memory");                        \
            __builtin_amdgcn_sched_barrier(0);                                        \
        } while (0)

    // One K-tile: snake quadrant order (0,0)->(0,1)->(1,1)->(1,0) for frag reuse.
    #define TILE(t, DOSTAGE)                                                          \
        do {                                                                          \
            READ_A((t) & 1, 0); READ_B((t) & 1, 0);                                   \
            if (DOSTAGE) STAGE_TILE(((t) & 1) ^ 1, (t) + 1);                          \
            PHASE_SYNC(); MFMA_Q(0, 0);                                               \
            __builtin_amdgcn_s_barrier();                                             \
            READ_B((t) & 1, 1);                                                       \
            PHASE_SYNC(); MFMA_Q(0, 1);                                               \
            __builtin_amdgcn_s_barrier();                                             \
            READ_A((t) & 1, 1);                                                       \
            PHASE_SYNC(); MFMA_Q(1, 1);                                               \
            __builtin_amdgcn_s_barrier();                                             \
            READ_B((t) & 1, 0);                                                       \
            PHASE_SYNC(); MFMA_Q(1, 0);                                               \
            if (DOSTAGE) asm volatile("s_waitcnt vmcnt(0)" ::: "memory");             \
            __builtin_amdgcn_s_barrier();                                             \
        } while (0)

    // Prologue: tile 0 into dbuf 0.
    STAGE_TILE(0, 0);
    asm volatile("s_waitcnt vmcnt(0)" ::: "memory");
    __builtin_amdgcn_s_barrier();

    TILE(0, 1);
    TILE(1, 1);
    TILE(2, 1);
    TILE(3, 1);
    TILE(4, 1);
    TILE(5, 1);
    TILE(6, 1);
    TILE(7, 0);

    // bias EMA-scale s[t] = (1 - p^(t+1))/(1-p); only 4 distinct t per thread:
    // t = (row0 + wm*128)/32 + (inner>>5), inner = mf*16 + (lane>>4)*4 + j,
    // and inner>>5 == mf>>1.
    float sc4[4];
    #pragma unroll
    for (int tt = 0; tt < 4; ++tt) {
        const int t_ = ((row0 + wm * 128) >> 5) + tt;
        sc4[tt] = (1.0f - __expf(-2.3025851f * (float)(t_ + 1))) * ISCALE;
    }
    float bv[4];
    #pragma unroll
    for (int nf = 0; nf < 4; ++nf)
        bv[nf] = bias[col0 + wn * 64 + nf * 16 + (lane & 15)];

    #pragma unroll
    for (int mf = 0; mf < 8; ++mf) {
        #pragma unroll
        for (int nf = 0; nf < 4; ++nf) {
            const int gcol = col0 + wn * 64 + nf * 16 + (lane & 15);
            #pragma unroll
            for (int j = 0; j < 4; ++j) {
                const int grow = row0 + wm * 128 + mf * 16 + ((lane >> 4) << 2) + j;
                Y[(size_t)grow * O_DIM + gcol] = acc[mf][nf][j] + sc4[mf >> 1] * bv[nf];
            }
        }
    }
}

extern "C" void kernel_launch(void* const* d_in, const int* in_sizes, int n_in,
                              void* d_out, int out_size, void* d_ws, size_t ws_size,
                              hipStream_t stream) {
    const float* X    = (const float*)d_in[0];
    const float* W    = (const float*)d_in[1];
    const float* bias = (const float*)d_in[2];
    float* Y = (float*)d_out;
    unsigned short* Wb = (unsigned short*)d_ws;                       // 512 KB
    unsigned short* Xv = (unsigned short*)((char*)d_ws + (1 << 20));  // 134 MB

    wcvt_kernel<<<dim3(O_DIM * I_DIM / (256 * 4)), dim3(256), 0, stream>>>(W, Wb);
    xema_kernel<<<dim3((T_DIM / STRIP) * 16), dim3(256), 0, stream>>>(X, Xv);
    gemm_kernel<<<dim3((M_DIM / BM) * (O_DIM / BN)), dim3(512), 0, stream>>>(Xv, Wb, bias, Y);
}